// Round 8
// baseline (548.394 us; speedup 1.0000x reference)
//
#include <hip/hip_runtime.h>

#define N_NODES 100000
#define E_EDGES 1600000
#define E_TOT   1700000   // edges + self loops
#define FDIM    128       // F_IN and HEADS*HID
#define C2      10        // classes
#define YPAD    16        // yl/yr row stride (one 64B line)
#define NEG     0.2f
#define LOG2E   1.44269504088896f
#define PCLAMP  80.0f

#define NDEG    ((E_TOT + 255) / 256)        // 6641 edge chunks
#define NWT     128                          // 32768 / 256
#define GB1     ((N_NODES + 63) / 64)        // 1563 gemm1 blocks
#define CSR_BLK 1024                         // k_csr grid (4 blocks/CU -> all co-resident)

typedef __attribute__((ext_vector_type(8))) short short8;
typedef __attribute__((ext_vector_type(4))) float f32x4;
typedef __attribute__((ext_vector_type(2))) float f32x2;

// 16-lane / 8-lane row reductions via DPP (pure VALU, no LDS pipe)
template <int CTRL>
__device__ __forceinline__ float dpp_add(float x) {
  return x + __int_as_float(
      __builtin_amdgcn_update_dpp(0, __float_as_int(x), CTRL, 0xF, 0xF, true));
}
__device__ __forceinline__ float row16_sum(float p) {
  p = dpp_add<0xB1>(p);
  p = dpp_add<0x4E>(p);
  p = dpp_add<0x141>(p);
  p = dpp_add<0x140>(p);
  return p;
}
__device__ __forceinline__ float row8_sum(float p) {
  p = dpp_add<0xB1>(p);    // xor 1 (quad_perm [1,0,3,2])
  p = dpp_add<0x4E>(p);    // xor 2 (quad_perm [2,3,0,1])
  p = dpp_add<0x141>(p);   // row_half_mirror: folds the two quads of each 8-lane group
  return p;
}

// fp32 -> bf16 (round-nearest-even), and packed bf16x2 -> float2
__device__ __forceinline__ unsigned short f2bf(float f) {
  unsigned int u = __float_as_uint(f);
  u += 0x7FFFu + ((u >> 16) & 1u);
  return (unsigned short)(u >> 16);
}
__device__ __forceinline__ f32x2 up2v(unsigned int v) {
  f32x2 r;
  r.x = __uint_as_float(v << 16);
  r.y = __uint_as_float(v & 0xFFFF0000u);
  return r;
}

#define SCAN_ITEMS 8
#define SCAN_CHUNK 2048
#define SCAN_NBLK  ((N_NODES + SCAN_CHUNK - 1) / SCAN_CHUNK)   // 49

// ---------------- W1 transpose + cnt zeroing + csr-sync init ----------------
__global__ __launch_bounds__(256) void k_prep_w(const float* __restrict__ W1l, const float* __restrict__ W1r,
                                                unsigned short* __restrict__ Wt, int* __restrict__ cnt,
                                                int* __restrict__ agg, int* __restrict__ done) {
  int i = blockIdx.x * 256 + threadIdx.x;
  int n = i & 255, k = i >> 8;
  float v = (n < 128) ? W1l[k * 128 + n] : W1r[k * 128 + (n - 128)];
  Wt[n * 128 + k] = f2bf(v);   // B^T layout: row n, contiguous k
  for (int c = i; c < N_NODES; c += NWT * 256) cnt[c] = 0;
  if (blockIdx.x == 0 && threadIdx.x < 64) {
    if (threadIdx.x < SCAN_NBLK) agg[threadIdx.x] = -1;   // lookback sentinel
    if (threadIdx.x == 63) *done = 0;
  }
}

// ---------------- fused: Layer-1 GEMM (blocks < GB1) + degree count (rest) ----------------
// Count is fire-and-forget (no epos): within-row order is canonicalized by agg1's sort.
__global__ __launch_bounds__(256) void k_gc(const float* __restrict__ x,
                                            const unsigned short* __restrict__ Wt,
                                            unsigned short* __restrict__ Hlb,
                                            unsigned short* __restrict__ Hrb,
                                            const int* __restrict__ ei, int* __restrict__ cnt) {
  int b = blockIdx.x;
  if (b >= GB1) {
    int tid = (b - GB1) * 256 + threadIdx.x;
    if (tid < E_TOT) {
      int d = (tid < E_EDGES) ? ei[E_EDGES + tid] : (tid - E_EDGES);
      atomicAdd(&cnt[d], 1);
    }
    return;
  }
  int w = threadIdx.x >> 6, lane = threadIdx.x & 63;
  int m = lane & 15, quad = lane >> 4;
  int row0 = b * 64 + w * 16;
  int arow = row0 + m;
  short8 A[4];
  bool aok = arow < N_NODES;
  const float4* ap = (const float4*)(x + (size_t)arow * FDIM + quad * 8);
#pragma unroll
  for (int c = 0; c < 4; c++) {
    short8 a = {};
    if (aok) {
      float4 v0 = ap[c * 8 + 0];
      float4 v1 = ap[c * 8 + 1];
      a[0] = (short)f2bf(v0.x); a[1] = (short)f2bf(v0.y);
      a[2] = (short)f2bf(v0.z); a[3] = (short)f2bf(v0.w);
      a[4] = (short)f2bf(v1.x); a[5] = (short)f2bf(v1.y);
      a[6] = (short)f2bf(v1.z); a[7] = (short)f2bf(v1.w);
    }
    A[c] = a;
  }

  int orow = row0 + quad * 4;
#pragma unroll
  for (int t0 = 0; t0 < 16; t0++) {
    const short8* bp = (const short8*)(Wt + (size_t)(t0 * 16 + m) * 128 + quad * 8);
    f32x4 acc = {0.f, 0.f, 0.f, 0.f};
#pragma unroll
    for (int c = 0; c < 4; c++)
      acc = __builtin_amdgcn_mfma_f32_16x16x32_bf16(A[c], bp[c * 4], acc, 0, 0, 0);
    int n0 = t0 * 16;
    unsigned short* dst = (n0 < 128) ? Hlb : Hrb;
    int col = (n0 < 128) ? n0 + m : (n0 - 128) + m;
#pragma unroll
    for (int r = 0; r < 4; r++) {
      int row = orow + r;
      if (row < N_NODES) dst[(size_t)row * FDIM + col] = f2bf(acc[r]);
    }
  }
}

// ---------------- fused CSR build: scan (decoupled lookback) + scatter ----------------
// Blocks 0..48 scan cnt -> row_ptr/wp, publish via agent-scope atomics; all 1024 blocks
// (co-resident: 4/CU) wait for done==49, then grid-stride scatter with atomic wp cursors.
__global__ __launch_bounds__(256) void k_csr(const int* __restrict__ cnt,
                                             const int* __restrict__ ei,
                                             int* __restrict__ row_ptr, int* __restrict__ wp,
                                             int* __restrict__ colA,
                                             int* __restrict__ agg, int* __restrict__ done) {
  int b = blockIdx.x, t = threadIdx.x;
  if (b < SCAN_NBLK) {
    int base = b * SCAN_CHUNK + t * SCAN_ITEMS;
    int vals[SCAN_ITEMS]; int ts = 0;
#pragma unroll
    for (int i = 0; i < SCAN_ITEMS; i++) {
      int idx = base + i;
      vals[i] = (idx < N_NODES) ? cnt[idx] : 0;
      ts += vals[i];
    }
    __shared__ int sd[256];
    sd[t] = ts; __syncthreads();
    for (int o = 1; o < 256; o <<= 1) {
      int v = 0;
      if (t >= o) v = sd[t - o];
      __syncthreads();
      sd[t] += v;
      __syncthreads();
    }
    // publish block total FIRST (publish-before-poll: no circular wait)
    if (t == 0)
      __hip_atomic_store(&agg[b], sd[255], __ATOMIC_RELEASE, __HIP_MEMORY_SCOPE_AGENT);
    // lookback: wave 0 sums all predecessors' totals (parallel, no serial chain)
    __shared__ int boffs;
    if (t < 64) {
      int v = 0;
      if (t < b) {
        while ((v = __hip_atomic_load(&agg[t], __ATOMIC_ACQUIRE, __HIP_MEMORY_SCOPE_AGENT)) < 0) {}
      }
      for (int o = 1; o < 64; o <<= 1) v += __shfl_xor(v, o);
      if (t == 0) boffs = v;
    }
    __syncthreads();
    int run = boffs + sd[t] - ts;
#pragma unroll
    for (int i = 0; i < SCAN_ITEMS; i++) {
      int idx = base + i;
      if (idx < N_NODES) { row_ptr[idx] = run; wp[idx] = run; }
      run += vals[i];
    }
    if (b == 0 && t == 0) row_ptr[N_NODES] = E_TOT;
    __syncthreads();
    __threadfence();
    if (t == 0) __hip_atomic_fetch_add(done, 1, __ATOMIC_ACQ_REL, __HIP_MEMORY_SCOPE_AGENT);
  }
  // all blocks: wait for scan completion (publishers are co-resident -> no deadlock)
  if (t == 0) {
    while (__hip_atomic_load(done, __ATOMIC_ACQUIRE, __HIP_MEMORY_SCOPE_AGENT) < SCAN_NBLK) {}
  }
  __syncthreads();
  for (int e = b * 256 + t; e < E_TOT; e += CSR_BLK * 256) {
    int s, d;
    if (e < E_EDGES) { s = ei[e]; d = ei[E_EDGES + e]; }
    else { s = e - E_EDGES; d = s; }
    colA[atomicAdd(&wp[d], 1)] = s;   // within-row order nondeterministic; agg1 sorts
  }
}

// ---------------- Layer-1 aggregation + in-wave CSR sort + fused layer-2 transform ----------------
// Champion structure (r4/r6): 1 node/wave, 64-lane rows, 2 ch/lane packed-f32, batch-8 gathers,
// LDS-staged W2 epilogue, pk_max leaky-ReLU. UNCHANGED.
__global__ __launch_bounds__(256) void k_agg1(const unsigned short* __restrict__ Hlb,
                                              const unsigned short* __restrict__ Hrb,
                                              const int* __restrict__ row_ptr, int* __restrict__ colA,
                                              const float* __restrict__ att, const float* __restrict__ bias,
                                              const float* __restrict__ W2l, const float* __restrict__ W2r,
                                              float* __restrict__ yl, float* __restrict__ yr) {
  __shared__ float hsh[4][FDIM];
  __shared__ int sidx[4][64];
  __shared__ float w2t[2][C2][132];   // transposed W2, +4 pad -> near-conflict-free b128 reads
  for (int i = threadIdx.x; i < FDIM * C2; i += 256) {
    int k = i / C2, cc = i - C2 * k;
    w2t[0][cc][k] = W2l[i];
    w2t[1][cc][k] = W2r[i];
  }
  __syncthreads();

  int w = threadIdx.x >> 6;
  int node = blockIdx.x * 4 + w;
  int lane = threadIdx.x & 63;
  int c0 = 2 * lane;
  const unsigned int* Hl32 = (const unsigned int*)Hlb;   // row = 64 uints
  const unsigned int* Hr32 = (const unsigned int*)Hrb;
  f32x2 xr = up2v(Hr32[((size_t)node << 6) + lane]);
  f32x2 av; av.x = att[c0] * LOG2E; av.y = att[c0 + 1] * LOG2E;
  int beg = row_ptr[node], end = row_ptr[node + 1];
  int deg = end - beg;
  bool small = deg <= 64;

  if (small) {
    // in-wave bitonic sort (canonical ascending order -> deterministic FP order)
    int v = (lane < deg) ? colA[beg + lane] : 0x7FFFFFFF;
#pragma unroll
    for (int k = 2; k <= 64; k <<= 1) {
#pragma unroll
      for (int j = k >> 1; j > 0; j >>= 1) {
        int other = __shfl_xor(v, j);
        bool up = ((lane & k) == 0);
        bool lower = ((lane & j) == 0);
        int mn = min(v, other), mx = max(v, other);
        v = (lower == up) ? mn : mx;
      }
    }
    sidx[w][lane] = v;                      // intra-wave: DS ops in order
    if (lane < deg) colA[beg + lane] = v;   // sorted row for agg2
  } else {
    if (lane == 0) {
      for (int i = beg + 1; i < end; i++) {
        int vv = colA[i];
        int j = i - 1;
        while (j >= beg && colA[j] > vv) { colA[j + 1] = colA[j]; j--; }
        colA[j + 1] = vv;
      }
    }
    __threadfence_block();
  }

  float l = 0.f;
  f32x2 acc = {0.f, 0.f};
  auto update = [&](unsigned int vv) {
    f32x2 xl = up2v(vv);
    f32x2 t = xl + xr;                       // v_pk_add_f32
    f32x2 u = t * NEG;                       // v_pk_mul_f32
    t = __builtin_elementwise_max(t, u);     // v_pk_max_f32: leaky = max(t, 0.2t)
    f32x2 m = t * av;                        // v_pk_mul_f32
    float p = row16_sum(m.x + m.y);
    float ww = __builtin_amdgcn_exp2f(fminf(p, PCLAMP));
    l += ww;
    acc += xl * ww;                          // v_pk_fma_f32
  };

  if (small) {
    const int* si = sidx[w];
    int j = 0;
    for (; j + 8 <= deg; j += 8) {
      unsigned int v0 = Hl32[((size_t)si[j + 0] << 6) + lane];
      unsigned int v1 = Hl32[((size_t)si[j + 1] << 6) + lane];
      unsigned int v2 = Hl32[((size_t)si[j + 2] << 6) + lane];
      unsigned int v3 = Hl32[((size_t)si[j + 3] << 6) + lane];
      unsigned int v4 = Hl32[((size_t)si[j + 4] << 6) + lane];
      unsigned int v5 = Hl32[((size_t)si[j + 5] << 6) + lane];
      unsigned int v6 = Hl32[((size_t)si[j + 6] << 6) + lane];
      unsigned int v7 = Hl32[((size_t)si[j + 7] << 6) + lane];
      update(v0); update(v1); update(v2); update(v3);
      update(v4); update(v5); update(v6); update(v7);
    }
    for (; j + 2 <= deg; j += 2) {
      unsigned int v0 = Hl32[((size_t)si[j + 0] << 6) + lane];
      unsigned int v1 = Hl32[((size_t)si[j + 1] << 6) + lane];
      update(v0); update(v1);
    }
    if (j < deg) update(Hl32[((size_t)si[j] << 6) + lane]);
  } else {
    for (int j = beg; j < end; j++) update(Hl32[((size_t)colA[j] << 6) + lane]);
  }

  float inv = 1.f / l;
  float ox = fmaxf(fmaf(acc.x, inv, bias[c0]),     0.f);   // fused ReLU
  float oy = fmaxf(fmaf(acc.y, inv, bias[c0 + 1]), 0.f);
  hsh[w][c0] = ox; hsh[w][c0 + 1] = oy;
  if (lane < 2 * C2) {
    bool isl = lane < C2;
    int cc = isl ? lane : lane - C2;
    const float4* wrow = (const float4*)&w2t[isl ? 0 : 1][cc][0];  // 528B row stride: 16B-aligned
    float a2 = 0.f;
    const float4* h4 = (const float4*)hsh[w];
#pragma unroll
    for (int k4 = 0; k4 < 32; k4++) {
      float4 hv = h4[k4];    // broadcast (same addr across lanes)
      float4 wv = wrow[k4];  // per-lane row, padded stride
      a2 = fmaf(hv.x, wv.x, a2);
      a2 = fmaf(hv.y, wv.y, a2);
      a2 = fmaf(hv.z, wv.z, a2);
      a2 = fmaf(hv.w, wv.w, a2);
    }
    float* Y = isl ? yl : yr;
    Y[(size_t)node * YPAD + cc] = a2;
  }
}

// ---------------- Layer-2 aggregation: 1 wave/node, 8-way edge-parallel, 2 ch/lane packed ----------------
__global__ __launch_bounds__(256) void k_agg2(const float* __restrict__ yl, const float* __restrict__ yr,
                                              const int* __restrict__ row_ptr, const int* __restrict__ colA,
                                              const float* __restrict__ att, const float* __restrict__ bias,
                                              float* __restrict__ outp) {
  int w = threadIdx.x >> 6;
  int node = blockIdx.x * 4 + w;
  if (node >= N_NODES) return;
  int lane = threadIdx.x & 63;
  int ch = 2 * (lane & 7);     // channel pair this lane owns
  int g  = lane >> 3;          // edge-group 0..7
  bool act = ch < C2;
  f32x2 xr = {0.f, 0.f};
  f32x2 a2 = {0.f, 0.f};
  if (act) {
    const float2* yr2 = (const float2*)(yr + (size_t)node * YPAD);
    float2 t = yr2[lane & 7];
    xr.x = t.x; xr.y = t.y;
    a2.x = att[ch] * LOG2E; a2.y = att[ch + 1] * LOG2E;
  }
  int beg = row_ptr[node], end = row_ptr[node + 1];
  float l = 0.f;
  f32x2 acc = {0.f, 0.f};
  const float2* ylL = (const float2*)yl + (lane & 7);   // row s at (s<<3) float2 units

  auto update = [&](f32x2 xl) {
    f32x2 t = xl + xr;                       // v_pk_add_f32
    f32x2 u = t * NEG;                       // v_pk_mul_f32
    t = __builtin_elementwise_max(t, u);     // v_pk_max_f32
    f32x2 m = t * a2;                        // v_pk_mul_f32
    float p = row8_sum(m.x + m.y);           // 8-lane group reduce (inactive lanes add 0)
    float wgt = __builtin_amdgcn_exp2f(fminf(p, PCLAMP));
    l += wgt;
    acc += xl * wgt;                         // v_pk_fma_f32
  };
  auto load = [&](int s) -> f32x2 {
    f32x2 r = {0.f, 0.f};
    if (act) {
      float2 t = ylL[(size_t)s << 3];        // yl row stride 16 floats = 8 float2
      r.x = t.x; r.y = t.y;
    }
    return r;
  };

  int j = beg + g;
  for (; j + 8 < end; j += 16) {             // 2 edges of this group: j, j+8
    int s0 = colA[j], s1 = colA[j + 8];
    f32x2 x0 = load(s0), x1 = load(s1);
    update(x0); update(x1);
  }
  if (j < end) update(load(colA[j]));

  // fixed combine tree across the 8 groups (deterministic)
  for (int o = 8; o <= 32; o <<= 1) {
    l     += __shfl_xor(l, o);
    acc.x += __shfl_xor(acc.x, o);
    acc.y += __shfl_xor(acc.y, o);
  }
  if (g == 0 && act) {
    float2 o;
    o.x = acc.x / l + bias[ch];
    o.y = acc.y / l + bias[ch + 1];
    *(float2*)(outp + (size_t)node * C2 + ch) = o;
  }
}

extern "C" void kernel_launch(void* const* d_in, const int* in_sizes, int n_in,
                              void* d_out, int out_size, void* d_ws, size_t ws_size,
                              hipStream_t stream) {
  const float* x    = (const float*)d_in[0];
  const int*   ei   = (const int*)d_in[1];
  const float* W1l  = (const float*)d_in[2];
  const float* W1r  = (const float*)d_in[3];
  const float* att1 = (const float*)d_in[4];
  const float* b1   = (const float*)d_in[5];
  const float* W2l  = (const float*)d_in[6];
  const float* W2r  = (const float*)d_in[7];
  const float* att2 = (const float*)d_in[8];
  const float* b2   = (const float*)d_in[9];
  float* out = (float*)d_out;

  char* ws = (char*)d_ws;
  size_t off = 0;
  auto take = [&](size_t bytes) -> char* {
    char* p = ws + off;
    off = (off + bytes + 511) & ~(size_t)511;
    return p;
  };
  unsigned short* Hlb = (unsigned short*)take((size_t)N_NODES * FDIM * sizeof(unsigned short)); // 25.6 MB
  unsigned short* Hrb = (unsigned short*)take((size_t)N_NODES * FDIM * sizeof(unsigned short)); // 25.6 MB
  unsigned short* Wt  = (unsigned short*)take((size_t)256 * 128 * sizeof(unsigned short));      // 64 KB
  float* yl      = (float*)take((size_t)N_NODES * YPAD * sizeof(float));   // 6.4 MB
  float* yr      = (float*)take((size_t)N_NODES * YPAD * sizeof(float));   // 6.4 MB
  int*   cnt     = (int*)take((size_t)N_NODES * sizeof(int));
  int*   row_ptr = (int*)take((size_t)(N_NODES + 1) * sizeof(int));
  int*   wp      = (int*)take((size_t)N_NODES * sizeof(int));
  int*   colA    = (int*)take((size_t)E_TOT * sizeof(int));
  int*   agg     = (int*)take(256);
  int*   done    = (int*)take(256);
  if (off > ws_size) return;

  k_prep_w <<<NWT, 256, 0, stream>>>(W1l, W1r, Wt, cnt, agg, done);
  k_gc     <<<GB1 + NDEG, 256, 0, stream>>>(x, Wt, Hlb, Hrb, ei, cnt);
  k_csr    <<<CSR_BLK, 256, 0, stream>>>(cnt, ei, row_ptr, wp, colA, agg, done);
  k_agg1   <<<(N_NODES + 3) / 4, 256, 0, stream>>>(Hlb, Hrb, row_ptr, colA, att1, b1, W2l, W2r, yl, yr);
  k_agg2   <<<(N_NODES + 3) / 4, 256, 0, stream>>>(yl, yr, row_ptr, colA, att2, b2, out);
}

// Round 9
// 394.873 us; speedup vs baseline: 1.3888x; 1.3888x over previous
//
#include <hip/hip_runtime.h>

#define N_NODES 100000
#define E_EDGES 1600000
#define E_TOT   1700000   // edges + self loops
#define FDIM    128       // F_IN and HEADS*HID
#define C2      10        // classes
#define YPAD    16        // yl/yr row stride (one 64B line)
#define NEG     0.2f
#define LOG2E   1.44269504088896f
#define PCLAMP  80.0f

#define NDEG    ((E_TOT + 255) / 256)        // 6641 edge chunks
#define NWT     128                          // 32768 / 256
#define GB1     ((N_NODES + 63) / 64)        // 1563 gemm1 blocks

typedef __attribute__((ext_vector_type(8))) short short8;
typedef __attribute__((ext_vector_type(4))) float f32x4;
typedef __attribute__((ext_vector_type(2))) float f32x2;

// 16-lane / 8-lane row reductions via DPP (pure VALU, no LDS pipe)
template <int CTRL>
__device__ __forceinline__ float dpp_add(float x) {
  return x + __int_as_float(
      __builtin_amdgcn_update_dpp(0, __float_as_int(x), CTRL, 0xF, 0xF, true));
}
__device__ __forceinline__ float row16_sum(float p) {
  p = dpp_add<0xB1>(p);
  p = dpp_add<0x4E>(p);
  p = dpp_add<0x141>(p);
  p = dpp_add<0x140>(p);
  return p;
}
__device__ __forceinline__ float row8_sum(float p) {
  p = dpp_add<0xB1>(p);    // xor 1 (quad_perm [1,0,3,2])
  p = dpp_add<0x4E>(p);    // xor 2 (quad_perm [2,3,0,1])
  p = dpp_add<0x141>(p);   // row_half_mirror: folds the two quads of each 8-lane group
  return p;
}

// fp32 -> bf16 (round-nearest-even), and packed bf16x2 -> float2
__device__ __forceinline__ unsigned short f2bf(float f) {
  unsigned int u = __float_as_uint(f);
  u += 0x7FFFu + ((u >> 16) & 1u);
  return (unsigned short)(u >> 16);
}
__device__ __forceinline__ f32x2 up2v(unsigned int v) {
  f32x2 r;
  r.x = __uint_as_float(v << 16);
  r.y = __uint_as_float(v & 0xFFFF0000u);
  return r;
}

#define SCAN_ITEMS 8
#define SCAN_CHUNK 2048
#define SCAN_NBLK  ((N_NODES + SCAN_CHUNK - 1) / SCAN_CHUNK)   // 49

// ---------------- W1 transpose + cnt zeroing + scan-lookback init ----------------
__global__ __launch_bounds__(256) void k_prep_w(const float* __restrict__ W1l, const float* __restrict__ W1r,
                                                unsigned short* __restrict__ Wt, int* __restrict__ cnt,
                                                int* __restrict__ agg) {
  int i = blockIdx.x * 256 + threadIdx.x;
  int n = i & 255, k = i >> 8;
  float v = (n < 128) ? W1l[k * 128 + n] : W1r[k * 128 + (n - 128)];
  Wt[n * 128 + k] = f2bf(v);   // B^T layout: row n, contiguous k
  for (int c = i; c < N_NODES; c += NWT * 256) cnt[c] = 0;
  if (blockIdx.x == 0 && threadIdx.x < SCAN_NBLK) agg[threadIdx.x] = -1;   // lookback sentinel
}

// ---------------- fused: Layer-1 GEMM (blocks < GB1) + degree count (rest) ----------------
// Atomic count hides under the co-resident gemm blocks (r8 lesson: never expose it).
__global__ __launch_bounds__(256) void k_gc(const float* __restrict__ x,
                                            const unsigned short* __restrict__ Wt,
                                            unsigned short* __restrict__ Hlb,
                                            unsigned short* __restrict__ Hrb,
                                            const int* __restrict__ ei, int* __restrict__ cnt,
                                            int* __restrict__ epos) {
  int b = blockIdx.x;
  if (b >= GB1) {
    int tid = (b - GB1) * 256 + threadIdx.x;
    if (tid < E_TOT) {
      int d = (tid < E_EDGES) ? ei[E_EDGES + tid] : (tid - E_EDGES);
      epos[tid] = atomicAdd(&cnt[d], 1);
    }
    return;
  }
  int w = threadIdx.x >> 6, lane = threadIdx.x & 63;
  int m = lane & 15, quad = lane >> 4;
  int row0 = b * 64 + w * 16;
  int arow = row0 + m;
  short8 A[4];
  bool aok = arow < N_NODES;
  const float4* ap = (const float4*)(x + (size_t)arow * FDIM + quad * 8);
#pragma unroll
  for (int c = 0; c < 4; c++) {
    short8 a = {};
    if (aok) {
      float4 v0 = ap[c * 8 + 0];
      float4 v1 = ap[c * 8 + 1];
      a[0] = (short)f2bf(v0.x); a[1] = (short)f2bf(v0.y);
      a[2] = (short)f2bf(v0.z); a[3] = (short)f2bf(v0.w);
      a[4] = (short)f2bf(v1.x); a[5] = (short)f2bf(v1.y);
      a[6] = (short)f2bf(v1.z); a[7] = (short)f2bf(v1.w);
    }
    A[c] = a;
  }

  int orow = row0 + quad * 4;
#pragma unroll
  for (int t0 = 0; t0 < 16; t0++) {
    const short8* bp = (const short8*)(Wt + (size_t)(t0 * 16 + m) * 128 + quad * 8);
    f32x4 acc = {0.f, 0.f, 0.f, 0.f};
#pragma unroll
    for (int c = 0; c < 4; c++)
      acc = __builtin_amdgcn_mfma_f32_16x16x32_bf16(A[c], bp[c * 4], acc, 0, 0, 0);
    int n0 = t0 * 16;
    unsigned short* dst = (n0 < 128) ? Hlb : Hrb;
    int col = (n0 < 128) ? n0 + m : (n0 - 128) + m;
#pragma unroll
    for (int r = 0; r < 4; r++) {
      int row = orow + r;
      if (row < N_NODES) dst[(size_t)row * FDIM + col] = f2bf(acc[r]);
    }
  }
}

// ---------------- fused scan: per-chunk scan + decoupled lookback (replaces scan1+scan3) ----------------
// Block b publishes its chunk total, then wave 0 spin-reads totals of blocks < b (earlier
// blocks are scheduled first -> forward progress guaranteed; validated in r8's scan phase).
__global__ __launch_bounds__(256) void k_scan(const int* __restrict__ cnt, int* __restrict__ row_ptr,
                                              int* __restrict__ agg) {
  int b = blockIdx.x, t = threadIdx.x;
  int base = b * SCAN_CHUNK + t * SCAN_ITEMS;
  int vals[SCAN_ITEMS]; int ts = 0;
#pragma unroll
  for (int i = 0; i < SCAN_ITEMS; i++) {
    int idx = base + i;
    vals[i] = (idx < N_NODES) ? cnt[idx] : 0;
    ts += vals[i];
  }
  __shared__ int sd[256];
  sd[t] = ts; __syncthreads();
  for (int o = 1; o < 256; o <<= 1) {
    int v = 0;
    if (t >= o) v = sd[t - o];
    __syncthreads();
    sd[t] += v;
    __syncthreads();
  }
  if (t == 0)
    __hip_atomic_store(&agg[b], sd[255], __ATOMIC_RELEASE, __HIP_MEMORY_SCOPE_AGENT);
  __shared__ int boffs;
  if (t < 64) {
    int v = 0;
    if (t < b) {   // b <= 48 < 64: one wave covers the full prefix
      while ((v = __hip_atomic_load(&agg[t], __ATOMIC_ACQUIRE, __HIP_MEMORY_SCOPE_AGENT)) < 0) {}
    }
    for (int o = 1; o < 64; o <<= 1) v += __shfl_xor(v, o);
    if (t == 0) boffs = v;
  }
  __syncthreads();
  int run = boffs + sd[t] - ts;
#pragma unroll
  for (int i = 0; i < SCAN_ITEMS; i++) {
    int idx = base + i;
    if (idx < N_NODES) row_ptr[idx] = run;
    run += vals[i];
  }
  if (b == 0 && t == 0) row_ptr[N_NODES] = E_TOT;
}

__global__ __launch_bounds__(256) void k_scatter(const int* __restrict__ ei,
                                                 const int* __restrict__ row_ptr,
                                                 const int* __restrict__ epos,
                                                 int* __restrict__ colA) {
  int tid = blockIdx.x * 256 + threadIdx.x;
  if (tid >= E_TOT) return;
  int s, d;
  if (tid < E_EDGES) { s = ei[tid]; d = ei[E_EDGES + tid]; }
  else { s = tid - E_EDGES; d = s; }
  colA[row_ptr[d] + epos[tid]] = s;
}

// ---------------- Layer-1 aggregation + in-wave CSR sort + fused layer-2 transform ----------------
// Champion structure (r4/r6). This round: per-edge addressing moved off the saturated VALU pipe —
// sidx holds pre-shifted byte offsets; readfirstlane -> SGPR row base -> saddr-form loads.
__global__ __launch_bounds__(256) void k_agg1(const unsigned short* __restrict__ Hlb,
                                              const unsigned short* __restrict__ Hrb,
                                              const int* __restrict__ row_ptr, int* __restrict__ colA,
                                              const float* __restrict__ att, const float* __restrict__ bias,
                                              const float* __restrict__ W2l, const float* __restrict__ W2r,
                                              float* __restrict__ yl, float* __restrict__ yr) {
  __shared__ float hsh[4][FDIM];
  __shared__ int sidx[4][64];
  __shared__ float w2t[2][C2][132];   // transposed W2, +4 pad -> near-conflict-free b128 reads
  for (int i = threadIdx.x; i < FDIM * C2; i += 256) {
    int k = i / C2, cc = i - C2 * k;
    w2t[0][cc][k] = W2l[i];
    w2t[1][cc][k] = W2r[i];
  }
  __syncthreads();

  int w = threadIdx.x >> 6;
  int node = blockIdx.x * 4 + w;
  int lane = threadIdx.x & 63;
  int c0 = 2 * lane;
  const unsigned int* Hl32 = (const unsigned int*)Hlb;   // row = 64 uints = 256 B
  const unsigned int* Hr32 = (const unsigned int*)Hrb;
  f32x2 xr = up2v(Hr32[((size_t)node << 6) + lane]);
  f32x2 av; av.x = att[c0] * LOG2E; av.y = att[c0 + 1] * LOG2E;
  int beg = row_ptr[node], end = row_ptr[node + 1];
  int deg = end - beg;
  bool small = deg <= 64;

  if (small) {
    // in-wave bitonic sort (canonical ascending order -> deterministic FP order)
    int v = (lane < deg) ? colA[beg + lane] : 0x7FFFFFFF;
#pragma unroll
    for (int k = 2; k <= 64; k <<= 1) {
#pragma unroll
      for (int j = k >> 1; j > 0; j >>= 1) {
        int other = __shfl_xor(v, j);
        bool up = ((lane & k) == 0);
        bool lower = ((lane & j) == 0);
        int mn = min(v, other), mx = max(v, other);
        v = (lower == up) ? mn : mx;
      }
    }
    sidx[w][lane] = v << 8;                 // PRE-SHIFTED byte offset (row = 256 B)
    if (lane < deg) colA[beg + lane] = v;   // sorted row for agg2
  } else {
    if (lane == 0) {
      for (int i = beg + 1; i < end; i++) {
        int vv = colA[i];
        int j = i - 1;
        while (j >= beg && colA[j] > vv) { colA[j + 1] = colA[j]; j--; }
        colA[j + 1] = vv;
      }
    }
    __threadfence_block();
  }

  float l = 0.f;
  f32x2 acc = {0.f, 0.f};
  auto update = [&](unsigned int vv) {
    f32x2 xl = up2v(vv);
    f32x2 t = xl + xr;                       // v_pk_add_f32
    f32x2 u = t * NEG;                       // v_pk_mul_f32
    t = __builtin_elementwise_max(t, u);     // v_pk_max_f32: leaky = max(t, 0.2t)
    f32x2 m = t * av;                        // v_pk_mul_f32
    float p = row16_sum(m.x + m.y);
    float ww = __builtin_amdgcn_exp2f(fminf(p, PCLAMP));
    l += ww;
    acc += xl * ww;                          // v_pk_fma_f32
  };
  // uniform byte-offset -> SGPR row base (1 VALU readfirstlane; 64-bit add on SALU)
  auto rowp = [&](int boff) -> const unsigned int* {
    return (const unsigned int*)((const char*)Hl32 +
                                 (size_t)(unsigned)__builtin_amdgcn_readfirstlane(boff));
  };

  if (small) {
    const int* si = sidx[w];
    int j = 0;
    for (; j + 8 <= deg; j += 8) {
      unsigned int v0 = rowp(si[j + 0])[lane];
      unsigned int v1 = rowp(si[j + 1])[lane];
      unsigned int v2 = rowp(si[j + 2])[lane];
      unsigned int v3 = rowp(si[j + 3])[lane];
      unsigned int v4 = rowp(si[j + 4])[lane];
      unsigned int v5 = rowp(si[j + 5])[lane];
      unsigned int v6 = rowp(si[j + 6])[lane];
      unsigned int v7 = rowp(si[j + 7])[lane];
      update(v0); update(v1); update(v2); update(v3);
      update(v4); update(v5); update(v6); update(v7);
    }
    for (; j + 2 <= deg; j += 2) {
      unsigned int v0 = rowp(si[j + 0])[lane];
      unsigned int v1 = rowp(si[j + 1])[lane];
      update(v0); update(v1);
    }
    if (j < deg) update(rowp(si[j])[lane]);
  } else {
    for (int j = beg; j < end; j++)
      update(rowp(colA[j] << 8)[lane]);
  }

  float inv = 1.f / l;
  float ox = fmaxf(fmaf(acc.x, inv, bias[c0]),     0.f);   // fused ReLU
  float oy = fmaxf(fmaf(acc.y, inv, bias[c0 + 1]), 0.f);
  hsh[w][c0] = ox; hsh[w][c0 + 1] = oy;
  if (lane < 2 * C2) {
    bool isl = lane < C2;
    int cc = isl ? lane : lane - C2;
    const float4* wrow = (const float4*)&w2t[isl ? 0 : 1][cc][0];  // 528B row stride: 16B-aligned
    float a2 = 0.f;
    const float4* h4 = (const float4*)hsh[w];
#pragma unroll
    for (int k4 = 0; k4 < 32; k4++) {
      float4 hv = h4[k4];    // broadcast (same addr across lanes)
      float4 wv = wrow[k4];  // per-lane row, padded stride
      a2 = fmaf(hv.x, wv.x, a2);
      a2 = fmaf(hv.y, wv.y, a2);
      a2 = fmaf(hv.z, wv.z, a2);
      a2 = fmaf(hv.w, wv.w, a2);
    }
    float* Y = isl ? yl : yr;
    Y[(size_t)node * YPAD + cc] = a2;
  }
}

// ---------------- Layer-2 aggregation: 1 wave/node, 8-way edge-parallel, 2 ch/lane packed ----------------
__global__ __launch_bounds__(256) void k_agg2(const float* __restrict__ yl, const float* __restrict__ yr,
                                              const int* __restrict__ row_ptr, const int* __restrict__ colA,
                                              const float* __restrict__ att, const float* __restrict__ bias,
                                              float* __restrict__ outp) {
  int w = threadIdx.x >> 6;
  int node = blockIdx.x * 4 + w;
  if (node >= N_NODES) return;
  int lane = threadIdx.x & 63;
  int ch = 2 * (lane & 7);     // channel pair this lane owns
  int g  = lane >> 3;          // edge-group 0..7
  bool act = ch < C2;
  f32x2 xr = {0.f, 0.f};
  f32x2 a2 = {0.f, 0.f};
  if (act) {
    const float2* yr2 = (const float2*)(yr + (size_t)node * YPAD);
    float2 t = yr2[lane & 7];
    xr.x = t.x; xr.y = t.y;
    a2.x = att[ch] * LOG2E; a2.y = att[ch + 1] * LOG2E;
  }
  int beg = row_ptr[node], end = row_ptr[node + 1];
  float l = 0.f;
  f32x2 acc = {0.f, 0.f};
  const float2* ylL = (const float2*)yl + (lane & 7);   // row s at (s<<3) float2 units

  auto update = [&](f32x2 xl) {
    f32x2 t = xl + xr;                       // v_pk_add_f32
    f32x2 u = t * NEG;                       // v_pk_mul_f32
    t = __builtin_elementwise_max(t, u);     // v_pk_max_f32
    f32x2 m = t * a2;                        // v_pk_mul_f32
    float p = row8_sum(m.x + m.y);           // 8-lane group reduce (inactive lanes add 0)
    float wgt = __builtin_amdgcn_exp2f(fminf(p, PCLAMP));
    l += wgt;
    acc += xl * wgt;                         // v_pk_fma_f32
  };
  auto load = [&](int s) -> f32x2 {
    f32x2 r = {0.f, 0.f};
    if (act) {
      float2 t = ylL[(size_t)s << 3];        // yl row stride 16 floats = 8 float2
      r.x = t.x; r.y = t.y;
    }
    return r;
  };

  int j = beg + g;
  for (; j + 8 < end; j += 16) {             // 2 edges of this group: j, j+8
    int s0 = colA[j], s1 = colA[j + 8];
    f32x2 x0 = load(s0), x1 = load(s1);
    update(x0); update(x1);
  }
  if (j < end) update(load(colA[j]));

  // fixed combine tree across the 8 groups (deterministic)
  for (int o = 8; o <= 32; o <<= 1) {
    l     += __shfl_xor(l, o);
    acc.x += __shfl_xor(acc.x, o);
    acc.y += __shfl_xor(acc.y, o);
  }
  if (g == 0 && act) {
    float2 o;
    o.x = acc.x / l + bias[ch];
    o.y = acc.y / l + bias[ch + 1];
    *(float2*)(outp + (size_t)node * C2 + ch) = o;
  }
}

extern "C" void kernel_launch(void* const* d_in, const int* in_sizes, int n_in,
                              void* d_out, int out_size, void* d_ws, size_t ws_size,
                              hipStream_t stream) {
  const float* x    = (const float*)d_in[0];
  const int*   ei   = (const int*)d_in[1];
  const float* W1l  = (const float*)d_in[2];
  const float* W1r  = (const float*)d_in[3];
  const float* att1 = (const float*)d_in[4];
  const float* b1   = (const float*)d_in[5];
  const float* W2l  = (const float*)d_in[6];
  const float* W2r  = (const float*)d_in[7];
  const float* att2 = (const float*)d_in[8];
  const float* b2   = (const float*)d_in[9];
  float* out = (float*)d_out;

  char* ws = (char*)d_ws;
  size_t off = 0;
  auto take = [&](size_t bytes) -> char* {
    char* p = ws + off;
    off = (off + bytes + 511) & ~(size_t)511;
    return p;
  };
  unsigned short* Hlb = (unsigned short*)take((size_t)N_NODES * FDIM * sizeof(unsigned short)); // 25.6 MB
  unsigned short* Hrb = (unsigned short*)take((size_t)N_NODES * FDIM * sizeof(unsigned short)); // 25.6 MB
  unsigned short* Wt  = (unsigned short*)take((size_t)256 * 128 * sizeof(unsigned short));      // 64 KB
  float* yl      = (float*)take((size_t)N_NODES * YPAD * sizeof(float));   // 6.4 MB
  float* yr      = (float*)take((size_t)N_NODES * YPAD * sizeof(float));   // 6.4 MB
  int*   cnt     = (int*)take((size_t)N_NODES * sizeof(int));
  int*   row_ptr = (int*)take((size_t)(N_NODES + 1) * sizeof(int));
  int*   colA    = (int*)take((size_t)E_TOT * sizeof(int));
  int*   epos    = (int*)take((size_t)E_TOT * sizeof(int));
  int*   agg     = (int*)take(256);
  if (off > ws_size) return;

  k_prep_w <<<NWT, 256, 0, stream>>>(W1l, W1r, Wt, cnt, agg);
  k_gc     <<<GB1 + NDEG, 256, 0, stream>>>(x, Wt, Hlb, Hrb, ei, cnt, epos);
  k_scan   <<<SCAN_NBLK, 256, 0, stream>>>(cnt, row_ptr, agg);
  k_scatter<<<(E_TOT + 255) / 256, 256, 0, stream>>>(ei, row_ptr, epos, colA);
  k_agg1   <<<(N_NODES + 3) / 4, 256, 0, stream>>>(Hlb, Hrb, row_ptr, colA, att1, b1, W2l, W2r, yl, yr);
  k_agg2   <<<(N_NODES + 3) / 4, 256, 0, stream>>>(yl, yr, row_ptr, colA, att2, b2, out);
}

// Round 10
// 388.553 us; speedup vs baseline: 1.4114x; 1.0163x over previous
//
#include <hip/hip_runtime.h>

#define N_NODES 100000
#define E_EDGES 1600000
#define E_TOT   1700000   // edges + self loops
#define FDIM    128       // F_IN and HEADS*HID
#define C2      10        // classes
#define YPAD    16        // yl/yr row stride (one 64B line)
#define NEG     0.2f
#define LOG2E   1.44269504088896f
#define PCLAMP  80.0f

#define NDEG    ((E_TOT + 255) / 256)        // 6641 edge chunks
#define NWT     128                          // 32768 / 256
#define GB1     ((N_NODES + 63) / 64)        // 1563 gemm1 blocks

typedef __attribute__((ext_vector_type(8))) short short8;
typedef __attribute__((ext_vector_type(4))) float f32x4;
typedef __attribute__((ext_vector_type(2))) float f32x2;

// 16-lane / 8-lane row reductions via DPP (pure VALU, no LDS pipe)
template <int CTRL>
__device__ __forceinline__ float dpp_add(float x) {
  return x + __int_as_float(
      __builtin_amdgcn_update_dpp(0, __float_as_int(x), CTRL, 0xF, 0xF, true));
}
__device__ __forceinline__ float row16_sum(float p) {
  p = dpp_add<0xB1>(p);
  p = dpp_add<0x4E>(p);
  p = dpp_add<0x141>(p);
  p = dpp_add<0x140>(p);
  return p;
}
__device__ __forceinline__ float row8_sum(float p) {
  p = dpp_add<0xB1>(p);    // xor 1 (quad_perm [1,0,3,2])
  p = dpp_add<0x4E>(p);    // xor 2 (quad_perm [2,3,0,1])
  p = dpp_add<0x141>(p);   // row_half_mirror: folds the two quads of each 8-lane group
  return p;
}

// fp32 -> bf16 (round-nearest-even), and packed bf16x2 -> float2
__device__ __forceinline__ unsigned short f2bf(float f) {
  unsigned int u = __float_as_uint(f);
  u += 0x7FFFu + ((u >> 16) & 1u);
  return (unsigned short)(u >> 16);
}
__device__ __forceinline__ f32x2 up2v(unsigned int v) {
  f32x2 r;
  r.x = __uint_as_float(v << 16);
  r.y = __uint_as_float(v & 0xFFFF0000u);
  return r;
}

#define SCAN_ITEMS 8
#define SCAN_CHUNK 2048
#define SCAN_NBLK  ((N_NODES + SCAN_CHUNK - 1) / SCAN_CHUNK)   // 49

// ---------------- W1 transpose + cnt zeroing + scan-lookback init ----------------
__global__ __launch_bounds__(256) void k_prep_w(const float* __restrict__ W1l, const float* __restrict__ W1r,
                                                unsigned short* __restrict__ Wt, int* __restrict__ cnt,
                                                int* __restrict__ agg) {
  int i = blockIdx.x * 256 + threadIdx.x;
  int n = i & 255, k = i >> 8;
  float v = (n < 128) ? W1l[k * 128 + n] : W1r[k * 128 + (n - 128)];
  Wt[n * 128 + k] = f2bf(v);   // B^T layout: row n, contiguous k
  for (int c = i; c < N_NODES; c += NWT * 256) cnt[c] = 0;
  if (blockIdx.x == 0 && threadIdx.x < SCAN_NBLK) agg[threadIdx.x] = -1;   // lookback sentinel
}

// ---------------- fused: Layer-1 GEMM (blocks < GB1) + degree count (rest) ----------------
// Atomic count hides under the co-resident gemm blocks (r8 lesson: never expose it).
__global__ __launch_bounds__(256) void k_gc(const float* __restrict__ x,
                                            const unsigned short* __restrict__ Wt,
                                            unsigned short* __restrict__ Hlb,
                                            unsigned short* __restrict__ Hrb,
                                            const int* __restrict__ ei, int* __restrict__ cnt,
                                            int* __restrict__ epos) {
  int b = blockIdx.x;
  if (b >= GB1) {
    int tid = (b - GB1) * 256 + threadIdx.x;
    if (tid < E_TOT) {
      int d = (tid < E_EDGES) ? ei[E_EDGES + tid] : (tid - E_EDGES);
      epos[tid] = atomicAdd(&cnt[d], 1);
    }
    return;
  }
  int w = threadIdx.x >> 6, lane = threadIdx.x & 63;
  int m = lane & 15, quad = lane >> 4;
  int row0 = b * 64 + w * 16;
  int arow = row0 + m;
  short8 A[4];
  bool aok = arow < N_NODES;
  const float4* ap = (const float4*)(x + (size_t)arow * FDIM + quad * 8);
#pragma unroll
  for (int c = 0; c < 4; c++) {
    short8 a = {};
    if (aok) {
      float4 v0 = ap[c * 8 + 0];
      float4 v1 = ap[c * 8 + 1];
      a[0] = (short)f2bf(v0.x); a[1] = (short)f2bf(v0.y);
      a[2] = (short)f2bf(v0.z); a[3] = (short)f2bf(v0.w);
      a[4] = (short)f2bf(v1.x); a[5] = (short)f2bf(v1.y);
      a[6] = (short)f2bf(v1.z); a[7] = (short)f2bf(v1.w);
    }
    A[c] = a;
  }

  int orow = row0 + quad * 4;
#pragma unroll
  for (int t0 = 0; t0 < 16; t0++) {
    const short8* bp = (const short8*)(Wt + (size_t)(t0 * 16 + m) * 128 + quad * 8);
    f32x4 acc = {0.f, 0.f, 0.f, 0.f};
#pragma unroll
    for (int c = 0; c < 4; c++)
      acc = __builtin_amdgcn_mfma_f32_16x16x32_bf16(A[c], bp[c * 4], acc, 0, 0, 0);
    int n0 = t0 * 16;
    unsigned short* dst = (n0 < 128) ? Hlb : Hrb;
    int col = (n0 < 128) ? n0 + m : (n0 - 128) + m;
#pragma unroll
    for (int r = 0; r < 4; r++) {
      int row = orow + r;
      if (row < N_NODES) dst[(size_t)row * FDIM + col] = f2bf(acc[r]);
    }
  }
}

// ---------------- fused scan: per-chunk scan + decoupled lookback ----------------
__global__ __launch_bounds__(256) void k_scan(const int* __restrict__ cnt, int* __restrict__ row_ptr,
                                              int* __restrict__ agg) {
  int b = blockIdx.x, t = threadIdx.x;
  int base = b * SCAN_CHUNK + t * SCAN_ITEMS;
  int vals[SCAN_ITEMS]; int ts = 0;
#pragma unroll
  for (int i = 0; i < SCAN_ITEMS; i++) {
    int idx = base + i;
    vals[i] = (idx < N_NODES) ? cnt[idx] : 0;
    ts += vals[i];
  }
  __shared__ int sd[256];
  sd[t] = ts; __syncthreads();
  for (int o = 1; o < 256; o <<= 1) {
    int v = 0;
    if (t >= o) v = sd[t - o];
    __syncthreads();
    sd[t] += v;
    __syncthreads();
  }
  if (t == 0)
    __hip_atomic_store(&agg[b], sd[255], __ATOMIC_RELEASE, __HIP_MEMORY_SCOPE_AGENT);
  __shared__ int boffs;
  if (t < 64) {
    int v = 0;
    if (t < b) {   // b <= 48 < 64: one wave covers the full prefix
      while ((v = __hip_atomic_load(&agg[t], __ATOMIC_ACQUIRE, __HIP_MEMORY_SCOPE_AGENT)) < 0) {}
    }
    for (int o = 1; o < 64; o <<= 1) v += __shfl_xor(v, o);
    if (t == 0) boffs = v;
  }
  __syncthreads();
  int run = boffs + sd[t] - ts;
#pragma unroll
  for (int i = 0; i < SCAN_ITEMS; i++) {
    int idx = base + i;
    if (idx < N_NODES) row_ptr[idx] = run;
    run += vals[i];
  }
  if (b == 0 && t == 0) row_ptr[N_NODES] = E_TOT;
}

__global__ __launch_bounds__(256) void k_scatter(const int* __restrict__ ei,
                                                 const int* __restrict__ row_ptr,
                                                 const int* __restrict__ epos,
                                                 int* __restrict__ colA) {
  int tid = blockIdx.x * 256 + threadIdx.x;
  if (tid >= E_TOT) return;
  int s, d;
  if (tid < E_EDGES) { s = ei[tid]; d = ei[E_EDGES + tid]; }
  else { s = tid - E_EDGES; d = s; }
  colA[row_ptr[d] + epos[tid]] = s;
}

// ---------------- Layer-1 aggregation + in-wave CSR sort + fused layer-2 transform ----------------
// Champion gather loop (r4/r6: plain per-lane indexed loads — r9's readfirstlane form stalled).
// This round: epilogue matvec split 2 lanes/output (40 active lanes, serial depth halved).
__global__ __launch_bounds__(256) void k_agg1(const unsigned short* __restrict__ Hlb,
                                              const unsigned short* __restrict__ Hrb,
                                              const int* __restrict__ row_ptr, int* __restrict__ colA,
                                              const float* __restrict__ att, const float* __restrict__ bias,
                                              const float* __restrict__ W2l, const float* __restrict__ W2r,
                                              float* __restrict__ yl, float* __restrict__ yr) {
  __shared__ float hsh[4][FDIM];
  __shared__ int sidx[4][64];
  __shared__ float w2t[2][C2][132];   // transposed W2, +4 pad -> near-conflict-free b128 reads
  for (int i = threadIdx.x; i < FDIM * C2; i += 256) {
    int k = i / C2, cc = i - C2 * k;
    w2t[0][cc][k] = W2l[i];
    w2t[1][cc][k] = W2r[i];
  }
  __syncthreads();

  int w = threadIdx.x >> 6;
  int node = blockIdx.x * 4 + w;
  int lane = threadIdx.x & 63;
  int c0 = 2 * lane;
  const unsigned int* Hl32 = (const unsigned int*)Hlb;   // row = 64 uints
  const unsigned int* Hr32 = (const unsigned int*)Hrb;
  f32x2 xr = up2v(Hr32[((size_t)node << 6) + lane]);
  f32x2 av; av.x = att[c0] * LOG2E; av.y = att[c0 + 1] * LOG2E;
  int beg = row_ptr[node], end = row_ptr[node + 1];
  int deg = end - beg;
  bool small = deg <= 64;

  if (small) {
    // in-wave bitonic sort (canonical ascending order -> deterministic FP order)
    int v = (lane < deg) ? colA[beg + lane] : 0x7FFFFFFF;
#pragma unroll
    for (int k = 2; k <= 64; k <<= 1) {
#pragma unroll
      for (int j = k >> 1; j > 0; j >>= 1) {
        int other = __shfl_xor(v, j);
        bool up = ((lane & k) == 0);
        bool lower = ((lane & j) == 0);
        int mn = min(v, other), mx = max(v, other);
        v = (lower == up) ? mn : mx;
      }
    }
    sidx[w][lane] = v;                      // intra-wave: DS ops in order
    if (lane < deg) colA[beg + lane] = v;   // sorted row for agg2
  } else {
    if (lane == 0) {
      for (int i = beg + 1; i < end; i++) {
        int vv = colA[i];
        int j = i - 1;
        while (j >= beg && colA[j] > vv) { colA[j + 1] = colA[j]; j--; }
        colA[j + 1] = vv;
      }
    }
    __threadfence_block();
  }

  float l = 0.f;
  f32x2 acc = {0.f, 0.f};
  auto update = [&](unsigned int vv) {
    f32x2 xl = up2v(vv);
    f32x2 t = xl + xr;                       // v_pk_add_f32
    f32x2 u = t * NEG;                       // v_pk_mul_f32
    t = __builtin_elementwise_max(t, u);     // v_pk_max_f32: leaky = max(t, 0.2t)
    f32x2 m = t * av;                        // v_pk_mul_f32
    float p = row16_sum(m.x + m.y);
    float ww = __builtin_amdgcn_exp2f(fminf(p, PCLAMP));
    l += ww;
    acc += xl * ww;                          // v_pk_fma_f32
  };

  if (small) {
    const int* si = sidx[w];
    int j = 0;
    for (; j + 8 <= deg; j += 8) {
      unsigned int v0 = Hl32[((size_t)si[j + 0] << 6) + lane];
      unsigned int v1 = Hl32[((size_t)si[j + 1] << 6) + lane];
      unsigned int v2 = Hl32[((size_t)si[j + 2] << 6) + lane];
      unsigned int v3 = Hl32[((size_t)si[j + 3] << 6) + lane];
      unsigned int v4 = Hl32[((size_t)si[j + 4] << 6) + lane];
      unsigned int v5 = Hl32[((size_t)si[j + 5] << 6) + lane];
      unsigned int v6 = Hl32[((size_t)si[j + 6] << 6) + lane];
      unsigned int v7 = Hl32[((size_t)si[j + 7] << 6) + lane];
      update(v0); update(v1); update(v2); update(v3);
      update(v4); update(v5); update(v6); update(v7);
    }
    for (; j + 2 <= deg; j += 2) {
      unsigned int v0 = Hl32[((size_t)si[j + 0] << 6) + lane];
      unsigned int v1 = Hl32[((size_t)si[j + 1] << 6) + lane];
      update(v0); update(v1);
    }
    if (j < deg) update(Hl32[((size_t)si[j] << 6) + lane]);
  } else {
    for (int j = beg; j < end; j++) update(Hl32[((size_t)colA[j] << 6) + lane]);
  }

  float inv = 1.f / l;
  float ox = fmaxf(fmaf(acc.x, inv, bias[c0]),     0.f);   // fused ReLU
  float oy = fmaxf(fmaf(acc.y, inv, bias[c0 + 1]), 0.f);
  hsh[w][c0] = ox; hsh[w][c0 + 1] = oy;
  // epilogue: 2 lanes per output (lane 2o: k4 0..15, lane 2o+1: k4 16..31), shfl combine
  if (lane < 4 * C2) {
    int o = lane >> 1;               // output 0..19
    int half = lane & 1;             // k-range half
    bool isl = o < C2;
    int cc = isl ? o : o - C2;
    const float4* wrow = (const float4*)&w2t[isl ? 0 : 1][cc][0];  // 528B row stride
    const float4* h4 = (const float4*)hsh[w];
    float a2 = 0.f;
    int k0 = half << 4;
#pragma unroll
    for (int k4 = 0; k4 < 16; k4++) {
      float4 hv = h4[k0 + k4];
      float4 wv = wrow[k0 + k4];
      a2 = fmaf(hv.x, wv.x, a2);
      a2 = fmaf(hv.y, wv.y, a2);
      a2 = fmaf(hv.z, wv.z, a2);
      a2 = fmaf(hv.w, wv.w, a2);
    }
    a2 += __shfl_xor(a2, 1);         // fixed tree: (low half)+(high half)
    if (half == 0) {
      float* Y = isl ? yl : yr;
      Y[(size_t)node * YPAD + cc] = a2;
    }
  }
}

// ---------------- Layer-2 aggregation: 1 wave/node, 8-way edge-parallel, 2 ch/lane packed ----------------
__global__ __launch_bounds__(256) void k_agg2(const float* __restrict__ yl, const float* __restrict__ yr,
                                              const int* __restrict__ row_ptr, const int* __restrict__ colA,
                                              const float* __restrict__ att, const float* __restrict__ bias,
                                              float* __restrict__ outp) {
  int w = threadIdx.x >> 6;
  int node = blockIdx.x * 4 + w;
  if (node >= N_NODES) return;
  int lane = threadIdx.x & 63;
  int ch = 2 * (lane & 7);     // channel pair this lane owns
  int g  = lane >> 3;          // edge-group 0..7
  bool act = ch < C2;
  f32x2 xr = {0.f, 0.f};
  f32x2 a2 = {0.f, 0.f};
  if (act) {
    const float2* yr2 = (const float2*)(yr + (size_t)node * YPAD);
    float2 t = yr2[lane & 7];
    xr.x = t.x; xr.y = t.y;
    a2.x = att[ch] * LOG2E; a2.y = att[ch + 1] * LOG2E;
  }
  int beg = row_ptr[node], end = row_ptr[node + 1];
  float l = 0.f;
  f32x2 acc = {0.f, 0.f};
  const float2* ylL = (const float2*)yl + (lane & 7);   // row s at (s<<3) float2 units

  auto update = [&](f32x2 xl) {
    f32x2 t = xl + xr;                       // v_pk_add_f32
    f32x2 u = t * NEG;                       // v_pk_mul_f32
    t = __builtin_elementwise_max(t, u);     // v_pk_max_f32
    f32x2 m = t * a2;                        // v_pk_mul_f32
    float p = row8_sum(m.x + m.y);           // 8-lane group reduce (inactive lanes add 0)
    float wgt = __builtin_amdgcn_exp2f(fminf(p, PCLAMP));
    l += wgt;
    acc += xl * wgt;                         // v_pk_fma_f32
  };
  auto load = [&](int s) -> f32x2 {
    f32x2 r = {0.f, 0.f};
    if (act) {
      float2 t = ylL[(size_t)s << 3];        // yl row stride 16 floats = 8 float2
      r.x = t.x; r.y = t.y;
    }
    return r;
  };

  int j = beg + g;
  for (; j + 8 < end; j += 16) {             // 2 edges of this group: j, j+8
    int s0 = colA[j], s1 = colA[j + 8];
    f32x2 x0 = load(s0), x1 = load(s1);
    update(x0); update(x1);
  }
  if (j < end) update(load(colA[j]));

  // fixed combine tree across the 8 groups (deterministic)
  for (int o = 8; o <= 32; o <<= 1) {
    l     += __shfl_xor(l, o);
    acc.x += __shfl_xor(acc.x, o);
    acc.y += __shfl_xor(acc.y, o);
  }
  if (g == 0 && act) {
    float2 o;
    o.x = acc.x / l + bias[ch];
    o.y = acc.y / l + bias[ch + 1];
    *(float2*)(outp + (size_t)node * C2 + ch) = o;
  }
}

extern "C" void kernel_launch(void* const* d_in, const int* in_sizes, int n_in,
                              void* d_out, int out_size, void* d_ws, size_t ws_size,
                              hipStream_t stream) {
  const float* x    = (const float*)d_in[0];
  const int*   ei   = (const int*)d_in[1];
  const float* W1l  = (const float*)d_in[2];
  const float* W1r  = (const float*)d_in[3];
  const float* att1 = (const float*)d_in[4];
  const float* b1   = (const float*)d_in[5];
  const float* W2l  = (const float*)d_in[6];
  const float* W2r  = (const float*)d_in[7];
  const float* att2 = (const float*)d_in[8];
  const float* b2   = (const float*)d_in[9];
  float* out = (float*)d_out;

  char* ws = (char*)d_ws;
  size_t off = 0;
  auto take = [&](size_t bytes) -> char* {
    char* p = ws + off;
    off = (off + bytes + 511) & ~(size_t)511;
    return p;
  };
  unsigned short* Hlb = (unsigned short*)take((size_t)N_NODES * FDIM * sizeof(unsigned short)); // 25.6 MB
  unsigned short* Hrb = (unsigned short*)take((size_t)N_NODES * FDIM * sizeof(unsigned short)); // 25.6 MB
  unsigned short* Wt  = (unsigned short*)take((size_t)256 * 128 * sizeof(unsigned short));      // 64 KB
  float* yl      = (float*)take((size_t)N_NODES * YPAD * sizeof(float));   // 6.4 MB
  float* yr      = (float*)take((size_t)N_NODES * YPAD * sizeof(float));   // 6.4 MB
  int*   cnt     = (int*)take((size_t)N_NODES * sizeof(int));
  int*   row_ptr = (int*)take((size_t)(N_NODES + 1) * sizeof(int));
  int*   colA    = (int*)take((size_t)E_TOT * sizeof(int));
  int*   epos    = (int*)take((size_t)E_TOT * sizeof(int));
  int*   agg     = (int*)take(256);
  if (off > ws_size) return;

  k_prep_w <<<NWT, 256, 0, stream>>>(W1l, W1r, Wt, cnt, agg);
  k_gc     <<<GB1 + NDEG, 256, 0, stream>>>(x, Wt, Hlb, Hrb, ei, cnt, epos);
  k_scan   <<<SCAN_NBLK, 256, 0, stream>>>(cnt, row_ptr, agg);
  k_scatter<<<(E_TOT + 255) / 256, 256, 0, stream>>>(ei, row_ptr, epos, colA);
  k_agg1   <<<(N_NODES + 3) / 4, 256, 0, stream>>>(Hlb, Hrb, row_ptr, colA, att1, b1, W2l, W2r, yl, yr);
  k_agg2   <<<(N_NODES + 3) / 4, 256, 0, stream>>>(yl, yr, row_ptr, colA, att2, b2, out);
}

// Round 11
// 378.560 us; speedup vs baseline: 1.4486x; 1.0264x over previous
//
#include <hip/hip_runtime.h>

#define N_NODES 100000
#define E_EDGES 1600000
#define E_TOT   1700000   // edges + self loops
#define FDIM    128       // F_IN and HEADS*HID
#define C2      10        // classes
#define YPAD    16        // yl/yr row stride (one 64B line)
#define NEG     0.2f
#define LOG2E   1.44269504088896f
#define PCLAMP  80.0f

#define NDEG    ((E_TOT + 255) / 256)        // 6641 edge chunks
#define NWT     128                          // 32768 / 256
#define GB4     ((N_NODES + 255) / 256)      // 391 gemm blocks (64 rows/wave, 256 rows/block)

typedef __attribute__((ext_vector_type(8))) short short8;
typedef __attribute__((ext_vector_type(4))) float f32x4;
typedef __attribute__((ext_vector_type(2))) float f32x2;

// 16-lane / 8-lane row reductions via DPP (pure VALU, no LDS pipe)
template <int CTRL>
__device__ __forceinline__ float dpp_add(float x) {
  return x + __int_as_float(
      __builtin_amdgcn_update_dpp(0, __float_as_int(x), CTRL, 0xF, 0xF, true));
}
__device__ __forceinline__ float row16_sum(float p) {
  p = dpp_add<0xB1>(p);
  p = dpp_add<0x4E>(p);
  p = dpp_add<0x141>(p);
  p = dpp_add<0x140>(p);
  return p;
}
__device__ __forceinline__ float row8_sum(float p) {
  p = dpp_add<0xB1>(p);    // xor 1 (quad_perm [1,0,3,2])
  p = dpp_add<0x4E>(p);    // xor 2 (quad_perm [2,3,0,1])
  p = dpp_add<0x141>(p);   // row_half_mirror: folds the two quads of each 8-lane group
  return p;
}

// fp32 -> bf16 (round-nearest-even), and packed bf16x2 -> float2
__device__ __forceinline__ unsigned short f2bf(float f) {
  unsigned int u = __float_as_uint(f);
  u += 0x7FFFu + ((u >> 16) & 1u);
  return (unsigned short)(u >> 16);
}
__device__ __forceinline__ f32x2 up2v(unsigned int v) {
  f32x2 r;
  r.x = __uint_as_float(v << 16);
  r.y = __uint_as_float(v & 0xFFFF0000u);
  return r;
}

#define SCAN_ITEMS 8
#define SCAN_CHUNK 2048
#define SCAN_NBLK  ((N_NODES + SCAN_CHUNK - 1) / SCAN_CHUNK)   // 49

// ---------------- W1 transpose + cnt zeroing + scan-lookback init ----------------
__global__ __launch_bounds__(256) void k_prep_w(const float* __restrict__ W1l, const float* __restrict__ W1r,
                                                unsigned short* __restrict__ Wt, int* __restrict__ cnt,
                                                int* __restrict__ agg) {
  int i = blockIdx.x * 256 + threadIdx.x;
  int n = i & 255, k = i >> 8;
  float v = (n < 128) ? W1l[k * 128 + n] : W1r[k * 128 + (n - 128)];
  Wt[n * 128 + k] = f2bf(v);   // B^T layout: row n, contiguous k
  for (int c = i; c < N_NODES; c += NWT * 256) cnt[c] = 0;
  if (blockIdx.x == 0 && threadIdx.x < SCAN_NBLK) agg[threadIdx.x] = -1;   // lookback sentinel
}

// ---------------- fused: Layer-1 GEMM (blocks < GB4) + degree count (rest) ----------------
// Register-blocked x4: one wave computes 64 rows (A = 4 groups in VGPRs), so each
// B-fragment load feeds 16 MFMA (was 4) and B-traffic drops 400 MB -> 100 MB.
__global__ __launch_bounds__(256) void k_gc(const float* __restrict__ x,
                                            const unsigned short* __restrict__ Wt,
                                            unsigned short* __restrict__ Hlb,
                                            unsigned short* __restrict__ Hrb,
                                            const int* __restrict__ ei, int* __restrict__ cnt,
                                            int* __restrict__ epos) {
  int b = blockIdx.x;
  if (b >= GB4) {
    int tid = (b - GB4) * 256 + threadIdx.x;
    if (tid < E_TOT) {
      int d = (tid < E_EDGES) ? ei[E_EDGES + tid] : (tid - E_EDGES);
      epos[tid] = atomicAdd(&cnt[d], 1);
    }
    return;
  }
  int w = threadIdx.x >> 6, lane = threadIdx.x & 63;
  int m = lane & 15, quad = lane >> 4;
  int wrow0 = b * 256 + w * 64;
  short8 A[4][4];   // [row-group][k-chunk]
#pragma unroll
  for (int g = 0; g < 4; g++) {
    int arow = wrow0 + g * 16 + m;
    bool aok = arow < N_NODES;
    const float4* ap = (const float4*)(x + (size_t)arow * FDIM + quad * 8);
#pragma unroll
    for (int c = 0; c < 4; c++) {
      short8 a = {};
      if (aok) {
        float4 v0 = ap[c * 8 + 0];
        float4 v1 = ap[c * 8 + 1];
        a[0] = (short)f2bf(v0.x); a[1] = (short)f2bf(v0.y);
        a[2] = (short)f2bf(v0.z); a[3] = (short)f2bf(v0.w);
        a[4] = (short)f2bf(v1.x); a[5] = (short)f2bf(v1.y);
        a[6] = (short)f2bf(v1.z); a[7] = (short)f2bf(v1.w);
      }
      A[g][c] = a;
    }
  }

#pragma unroll
  for (int t0 = 0; t0 < 16; t0++) {
    const short8* bp = (const short8*)(Wt + (size_t)(t0 * 16 + m) * 128 + quad * 8);
    short8 B0 = bp[0], B1 = bp[4], B2 = bp[8], B3 = bp[12];
    int n0 = t0 * 16;
    unsigned short* dst = (n0 < 128) ? Hlb : Hrb;
    int col = (n0 < 128) ? n0 + m : (n0 - 128) + m;
#pragma unroll
    for (int g = 0; g < 4; g++) {
      f32x4 acc = {0.f, 0.f, 0.f, 0.f};
      acc = __builtin_amdgcn_mfma_f32_16x16x32_bf16(A[g][0], B0, acc, 0, 0, 0);
      acc = __builtin_amdgcn_mfma_f32_16x16x32_bf16(A[g][1], B1, acc, 0, 0, 0);
      acc = __builtin_amdgcn_mfma_f32_16x16x32_bf16(A[g][2], B2, acc, 0, 0, 0);
      acc = __builtin_amdgcn_mfma_f32_16x16x32_bf16(A[g][3], B3, acc, 0, 0, 0);
      int orow = wrow0 + g * 16 + quad * 4;
#pragma unroll
      for (int r = 0; r < 4; r++) {
        int row = orow + r;
        if (row < N_NODES) dst[(size_t)row * FDIM + col] = f2bf(acc[r]);
      }
    }
  }
}

// ---------------- fused scan: per-chunk scan + decoupled lookback ----------------
__global__ __launch_bounds__(256) void k_scan(const int* __restrict__ cnt, int* __restrict__ row_ptr,
                                              int* __restrict__ agg) {
  int b = blockIdx.x, t = threadIdx.x;
  int base = b * SCAN_CHUNK + t * SCAN_ITEMS;
  int vals[SCAN_ITEMS]; int ts = 0;
#pragma unroll
  for (int i = 0; i < SCAN_ITEMS; i++) {
    int idx = base + i;
    vals[i] = (idx < N_NODES) ? cnt[idx] : 0;
    ts += vals[i];
  }
  __shared__ int sd[256];
  sd[t] = ts; __syncthreads();
  for (int o = 1; o < 256; o <<= 1) {
    int v = 0;
    if (t >= o) v = sd[t - o];
    __syncthreads();
    sd[t] += v;
    __syncthreads();
  }
  if (t == 0)
    __hip_atomic_store(&agg[b], sd[255], __ATOMIC_RELEASE, __HIP_MEMORY_SCOPE_AGENT);
  __shared__ int boffs;
  if (t < 64) {
    int v = 0;
    if (t < b) {   // b <= 48 < 64: one wave covers the full prefix
      while ((v = __hip_atomic_load(&agg[t], __ATOMIC_ACQUIRE, __HIP_MEMORY_SCOPE_AGENT)) < 0) {}
    }
    for (int o = 1; o < 64; o <<= 1) v += __shfl_xor(v, o);
    if (t == 0) boffs = v;
  }
  __syncthreads();
  int run = boffs + sd[t] - ts;
#pragma unroll
  for (int i = 0; i < SCAN_ITEMS; i++) {
    int idx = base + i;
    if (idx < N_NODES) row_ptr[idx] = run;
    run += vals[i];
  }
  if (b == 0 && t == 0) row_ptr[N_NODES] = E_TOT;
}

__global__ __launch_bounds__(256) void k_scatter(const int* __restrict__ ei,
                                                 const int* __restrict__ row_ptr,
                                                 const int* __restrict__ epos,
                                                 int* __restrict__ colA) {
  int tid = blockIdx.x * 256 + threadIdx.x;
  if (tid >= E_TOT) return;
  int s, d;
  if (tid < E_EDGES) { s = ei[tid]; d = ei[E_EDGES + tid]; }
  else { s = tid - E_EDGES; d = s; }
  colA[row_ptr[d] + epos[tid]] = s;
}

// ---------------- Layer-1 aggregation + in-wave CSR sort + fused layer-2 transform ----------------
// Champion gather loop; 2-lane-split epilogue (r10). This round: w2t high half staggered
// to element 68 so half-pair lanes start 4 banks apart (was same bank -> forced conflicts).
__global__ __launch_bounds__(256) void k_agg1(const unsigned short* __restrict__ Hlb,
                                              const unsigned short* __restrict__ Hrb,
                                              const int* __restrict__ row_ptr, int* __restrict__ colA,
                                              const float* __restrict__ att, const float* __restrict__ bias,
                                              const float* __restrict__ W2l, const float* __restrict__ W2r,
                                              float* __restrict__ yl, float* __restrict__ yr) {
  __shared__ float hsh[4][FDIM];
  __shared__ int sidx[4][64];
  __shared__ float w2t[2][C2][132];   // transposed W2; halves at [0..63] and [68..131]
  for (int i = threadIdx.x; i < FDIM * C2; i += 256) {
    int k = i / C2, cc = i - C2 * k;
    int kk = k + ((k >> 6) << 2);     // high half staggered +4 floats
    w2t[0][cc][kk] = W2l[i];
    w2t[1][cc][kk] = W2r[i];
  }
  __syncthreads();

  int w = threadIdx.x >> 6;
  int node = blockIdx.x * 4 + w;
  int lane = threadIdx.x & 63;
  int c0 = 2 * lane;
  const unsigned int* Hl32 = (const unsigned int*)Hlb;   // row = 64 uints
  const unsigned int* Hr32 = (const unsigned int*)Hrb;
  f32x2 xr = up2v(Hr32[((size_t)node << 6) + lane]);
  f32x2 av; av.x = att[c0] * LOG2E; av.y = att[c0 + 1] * LOG2E;
  int beg = row_ptr[node], end = row_ptr[node + 1];
  int deg = end - beg;
  bool small = deg <= 64;

  if (small) {
    // in-wave bitonic sort (canonical ascending order -> deterministic FP order)
    int v = (lane < deg) ? colA[beg + lane] : 0x7FFFFFFF;
#pragma unroll
    for (int k = 2; k <= 64; k <<= 1) {
#pragma unroll
      for (int j = k >> 1; j > 0; j >>= 1) {
        int other = __shfl_xor(v, j);
        bool up = ((lane & k) == 0);
        bool lower = ((lane & j) == 0);
        int mn = min(v, other), mx = max(v, other);
        v = (lower == up) ? mn : mx;
      }
    }
    sidx[w][lane] = v;                      // intra-wave: DS ops in order
    if (lane < deg) colA[beg + lane] = v;   // sorted row for agg2
  } else {
    if (lane == 0) {
      for (int i = beg + 1; i < end; i++) {
        int vv = colA[i];
        int j = i - 1;
        while (j >= beg && colA[j] > vv) { colA[j + 1] = colA[j]; j--; }
        colA[j + 1] = vv;
      }
    }
    __threadfence_block();
  }

  float l = 0.f;
  f32x2 acc = {0.f, 0.f};
  auto update = [&](unsigned int vv) {
    f32x2 xl = up2v(vv);
    f32x2 t = xl + xr;                       // v_pk_add_f32
    f32x2 u = t * NEG;                       // v_pk_mul_f32
    t = __builtin_elementwise_max(t, u);     // v_pk_max_f32: leaky = max(t, 0.2t)
    f32x2 m = t * av;                        // v_pk_mul_f32
    float p = row16_sum(m.x + m.y);
    float ww = __builtin_amdgcn_exp2f(fminf(p, PCLAMP));
    l += ww;
    acc += xl * ww;                          // v_pk_fma_f32
  };

  if (small) {
    const int* si = sidx[w];
    int j = 0;
    for (; j + 8 <= deg; j += 8) {
      unsigned int v0 = Hl32[((size_t)si[j + 0] << 6) + lane];
      unsigned int v1 = Hl32[((size_t)si[j + 1] << 6) + lane];
      unsigned int v2 = Hl32[((size_t)si[j + 2] << 6) + lane];
      unsigned int v3 = Hl32[((size_t)si[j + 3] << 6) + lane];
      unsigned int v4 = Hl32[((size_t)si[j + 4] << 6) + lane];
      unsigned int v5 = Hl32[((size_t)si[j + 5] << 6) + lane];
      unsigned int v6 = Hl32[((size_t)si[j + 6] << 6) + lane];
      unsigned int v7 = Hl32[((size_t)si[j + 7] << 6) + lane];
      update(v0); update(v1); update(v2); update(v3);
      update(v4); update(v5); update(v6); update(v7);
    }
    for (; j + 2 <= deg; j += 2) {
      unsigned int v0 = Hl32[((size_t)si[j + 0] << 6) + lane];
      unsigned int v1 = Hl32[((size_t)si[j + 1] << 6) + lane];
      update(v0); update(v1);
    }
    if (j < deg) update(Hl32[((size_t)si[j] << 6) + lane]);
  } else {
    for (int j = beg; j < end; j++) update(Hl32[((size_t)colA[j] << 6) + lane]);
  }

  float inv = 1.f / l;
  float ox = fmaxf(fmaf(acc.x, inv, bias[c0]),     0.f);   // fused ReLU
  float oy = fmaxf(fmaf(acc.y, inv, bias[c0 + 1]), 0.f);
  hsh[w][c0] = ox; hsh[w][c0 + 1] = oy;
  // epilogue: 2 lanes per output (half 0: k 0..63, half 1: k 64..127), shfl combine
  if (lane < 4 * C2) {
    int o = lane >> 1;               // output 0..19
    int half = lane & 1;             // k-range half
    bool isl = o < C2;
    int cc = isl ? o : o - C2;
    const float4* wrow = (const float4*)&w2t[isl ? 0 : 1][cc][0];
    const float4* h4 = (const float4*)hsh[w];
    float a2 = 0.f;
    int k0 = half << 4;              // hsh float4 base
    int kw = half * 17;              // w2t float4 base (staggered half at elem 68)
#pragma unroll
    for (int k4 = 0; k4 < 16; k4++) {
      float4 hv = h4[k0 + k4];
      float4 wv = wrow[kw + k4];
      a2 = fmaf(hv.x, wv.x, a2);
      a2 = fmaf(hv.y, wv.y, a2);
      a2 = fmaf(hv.z, wv.z, a2);
      a2 = fmaf(hv.w, wv.w, a2);
    }
    a2 += __shfl_xor(a2, 1);         // fixed tree: (low half)+(high half)
    if (half == 0) {
      float* Y = isl ? yl : yr;
      Y[(size_t)node * YPAD + cc] = a2;
    }
  }
}

// ---------------- Layer-2 aggregation: 1 wave/node, 8-way edge-parallel, 2 ch/lane packed ----------------
__global__ __launch_bounds__(256) void k_agg2(const float* __restrict__ yl, const float* __restrict__ yr,
                                              const int* __restrict__ row_ptr, const int* __restrict__ colA,
                                              const float* __restrict__ att, const float* __restrict__ bias,
                                              float* __restrict__ outp) {
  int w = threadIdx.x >> 6;
  int node = blockIdx.x * 4 + w;
  if (node >= N_NODES) return;
  int lane = threadIdx.x & 63;
  int ch = 2 * (lane & 7);     // channel pair this lane owns
  int g  = lane >> 3;          // edge-group 0..7
  bool act = ch < C2;
  f32x2 xr = {0.f, 0.f};
  f32x2 a2 = {0.f, 0.f};
  if (act) {
    const float2* yr2 = (const float2*)(yr + (size_t)node * YPAD);
    float2 t = yr2[lane & 7];
    xr.x = t.x; xr.y = t.y;
    a2.x = att[ch] * LOG2E; a2.y = att[ch + 1] * LOG2E;
  }
  int beg = row_ptr[node], end = row_ptr[node + 1];
  float l = 0.f;
  f32x2 acc = {0.f, 0.f};
  const float2* ylL = (const float2*)yl + (lane & 7);   // row s at (s<<3) float2 units

  auto update = [&](f32x2 xl) {
    f32x2 t = xl + xr;                       // v_pk_add_f32
    f32x2 u = t * NEG;                       // v_pk_mul_f32
    t = __builtin_elementwise_max(t, u);     // v_pk_max_f32
    f32x2 m = t * a2;                        // v_pk_mul_f32
    float p = row8_sum(m.x + m.y);           // 8-lane group reduce (inactive lanes add 0)
    float wgt = __builtin_amdgcn_exp2f(fminf(p, PCLAMP));
    l += wgt;
    acc += xl * wgt;                         // v_pk_fma_f32
  };
  auto load = [&](int s) -> f32x2 {
    f32x2 r = {0.f, 0.f};
    if (act) {
      float2 t = ylL[(size_t)s << 3];        // yl row stride 16 floats = 8 float2
      r.x = t.x; r.y = t.y;
    }
    return r;
  };

  int j = beg + g;
  for (; j + 8 < end; j += 16) {             // 2 edges of this group: j, j+8
    int s0 = colA[j], s1 = colA[j + 8];
    f32x2 x0 = load(s0), x1 = load(s1);
    update(x0); update(x1);
  }
  if (j < end) update(load(colA[j]));

  // fixed combine tree across the 8 groups (deterministic)
  for (int o = 8; o <= 32; o <<= 1) {
    l     += __shfl_xor(l, o);
    acc.x += __shfl_xor(acc.x, o);
    acc.y += __shfl_xor(acc.y, o);
  }
  if (g == 0 && act) {
    float2 o;
    o.x = acc.x / l + bias[ch];
    o.y = acc.y / l + bias[ch + 1];
    *(float2*)(outp + (size_t)node * C2 + ch) = o;
  }
}

extern "C" void kernel_launch(void* const* d_in, const int* in_sizes, int n_in,
                              void* d_out, int out_size, void* d_ws, size_t ws_size,
                              hipStream_t stream) {
  const float* x    = (const float*)d_in[0];
  const int*   ei   = (const int*)d_in[1];
  const float* W1l  = (const float*)d_in[2];
  const float* W1r  = (const float*)d_in[3];
  const float* att1 = (const float*)d_in[4];
  const float* b1   = (const float*)d_in[5];
  const float* W2l  = (const float*)d_in[6];
  const float* W2r  = (const float*)d_in[7];
  const float* att2 = (const float*)d_in[8];
  const float* b2   = (const float*)d_in[9];
  float* out = (float*)d_out;

  char* ws = (char*)d_ws;
  size_t off = 0;
  auto take = [&](size_t bytes) -> char* {
    char* p = ws + off;
    off = (off + bytes + 511) & ~(size_t)511;
    return p;
  };
  unsigned short* Hlb = (unsigned short*)take((size_t)N_NODES * FDIM * sizeof(unsigned short)); // 25.6 MB
  unsigned short* Hrb = (unsigned short*)take((size_t)N_NODES * FDIM * sizeof(unsigned short)); // 25.6 MB
  unsigned short* Wt  = (unsigned short*)take((size_t)256 * 128 * sizeof(unsigned short));      // 64 KB
  float* yl      = (float*)take((size_t)N_NODES * YPAD * sizeof(float));   // 6.4 MB
  float* yr      = (float*)take((size_t)N_NODES * YPAD * sizeof(float));   // 6.4 MB
  int*   cnt     = (int*)take((size_t)N_NODES * sizeof(int));
  int*   row_ptr = (int*)take((size_t)(N_NODES + 1) * sizeof(int));
  int*   colA    = (int*)take((size_t)E_TOT * sizeof(int));
  int*   epos    = (int*)take((size_t)E_TOT * sizeof(int));
  int*   agg     = (int*)take(256);
  if (off > ws_size) return;

  k_prep_w <<<NWT, 256, 0, stream>>>(W1l, W1r, Wt, cnt, agg);
  k_gc     <<<GB4 + NDEG, 256, 0, stream>>>(x, Wt, Hlb, Hrb, ei, cnt, epos);
  k_scan   <<<SCAN_NBLK, 256, 0, stream>>>(cnt, row_ptr, agg);
  k_scatter<<<(E_TOT + 255) / 256, 256, 0, stream>>>(ei, row_ptr, epos, colA);
  k_agg1   <<<(N_NODES + 3) / 4, 256, 0, stream>>>(Hlb, Hrb, row_ptr, colA, att1, b1, W2l, W2r, yl, yr);
  k_agg2   <<<(N_NODES + 3) / 4, 256, 0, stream>>>(yl, yr, row_ptr, colA, att2, b2, out);
}